// Round 4
// baseline (327.474 us; speedup 1.0000x reference)
//
#include <hip/hip_runtime.h>
#include <hip/hip_bf16.h>

#define D_DIM 512
#define K_CL  2048
#define BM    32

#define AS1 __attribute__((address_space(1)))
#define AS3 __attribute__((address_space(3)))

typedef short s8v __attribute__((ext_vector_type(8)));
typedef float f4v __attribute__((ext_vector_type(4)));

__device__ __forceinline__ void gload16(const void* g, void* l) {
    // async global->LDS, 16B/lane; LDS dest = wave-uniform base + lane*16
    __builtin_amdgcn_global_load_lds((const AS1 void*)g, (AS3 void*)l, 16, 0, 0);
}

// ---- prep F: fp32 -> bf16 fragment-packed A image + row sum-of-squares -----
// Packed A: per 32-row block rb, per chunk c (32 k): 2 KB block at ushort idx
// rb*16384 + c*1024 + row*32 + j*8   (row 0..31, j = k-octet 0..3)
__global__ void prep_f_kernel(const float* __restrict__ src,
                              ushort* __restrict__ dst,
                              float* __restrict__ norms,
                              int nrows) {
    int row  = (int)((blockIdx.x * blockDim.x + threadIdx.x) >> 6);
    int lane = threadIdx.x & 63;
    if (row >= nrows) return;

    const float* s = src + (size_t)row * D_DIM + lane * 8;
    float4 v0 = *reinterpret_cast<const float4*>(s);
    float4 v1 = *reinterpret_cast<const float4*>(s + 4);

    float ss = v0.x * v0.x + v0.y * v0.y + v0.z * v0.z + v0.w * v0.w
             + v1.x * v1.x + v1.y * v1.y + v1.z * v1.z + v1.w * v1.w;

    alignas(16) __hip_bfloat16 h[8];
    h[0] = __float2bfloat16(v0.x); h[1] = __float2bfloat16(v0.y);
    h[2] = __float2bfloat16(v0.z); h[3] = __float2bfloat16(v0.w);
    h[4] = __float2bfloat16(v1.x); h[5] = __float2bfloat16(v1.y);
    h[6] = __float2bfloat16(v1.z); h[7] = __float2bfloat16(v1.w);

    // lane covers k = lane*8..+7  ->  c = lane>>2, j = lane&3
    const size_t di = (size_t)(row >> 5) * 16384 + (lane >> 2) * 1024
                    + (row & 31) * 32 + (lane & 3) * 8;
    *reinterpret_cast<uint4*>(dst + di) = *reinterpret_cast<const uint4*>(h);

    #pragma unroll
    for (int off = 32; off > 0; off >>= 1) ss += __shfl_down(ss, off, 64);
    if (lane == 0) norms[row] = ss;
}

// ---- prep P: fp32 -> bf16 fragment-packed B blocks + col sum-of-squares ----
// Packed B: per col-tile ct (16 cols), per chunk c: 1 KB block at ushort idx
// (ct*16 + c)*512 + ln*8, where lane ln holds P[ct*16 + (ln&15)][c*32 + (ln>>4)*8 ..+7]
__global__ void prep_p_kernel(const float* __restrict__ src,
                              ushort* __restrict__ dst,
                              float* __restrict__ norms) {
    __shared__ float pn[4][16];
    const int ct = blockIdx.x;            // col-tile 0..127
    const int w  = threadIdx.x >> 6;      // 0..3
    const int ln = threadIdx.x & 63;
    const int lr = ln & 15;
    const int j  = ln >> 4;

    float ss = 0.f;
    #pragma unroll
    for (int cc = 0; cc < 4; ++cc) {
        const int c = w * 4 + cc;
        const float* s = src + (size_t)(ct * 16 + lr) * D_DIM + c * 32 + j * 8;
        float4 v0 = *reinterpret_cast<const float4*>(s);
        float4 v1 = *reinterpret_cast<const float4*>(s + 4);
        ss += v0.x * v0.x + v0.y * v0.y + v0.z * v0.z + v0.w * v0.w
            + v1.x * v1.x + v1.y * v1.y + v1.z * v1.z + v1.w * v1.w;
        alignas(16) __hip_bfloat16 h[8];
        h[0] = __float2bfloat16(v0.x); h[1] = __float2bfloat16(v0.y);
        h[2] = __float2bfloat16(v0.z); h[3] = __float2bfloat16(v0.w);
        h[4] = __float2bfloat16(v1.x); h[5] = __float2bfloat16(v1.y);
        h[6] = __float2bfloat16(v1.z); h[7] = __float2bfloat16(v1.w);
        *reinterpret_cast<uint4*>(dst + (size_t)(ct * 16 + c) * 512 + ln * 8) =
            *reinterpret_cast<const uint4*>(h);
    }

    // sum over j (lanes 16 apart hold same col, different octets)
    ss += __shfl_xor(ss, 16, 64);
    ss += __shfl_xor(ss, 32, 64);
    if (j == 0) pn[w][lr] = ss;
    __syncthreads();
    if (threadIdx.x < 16)
        norms[ct * 16 + threadIdx.x] = pn[0][threadIdx.x] + pn[1][threadIdx.x]
                                     + pn[2][threadIdx.x] + pn[3][threadIdx.x];
}

// ------------- fused bf16 GEMM (F . P^T) + distance/sim/softmax --------------
// Block: 32 rows x ALL 2048 cols, 8 waves, each wave owns 256 contiguous cols
// (16 col-tiles). NO barriers in K-loop: B frags stream L2 -> VGPR directly
// (frag-packed, 1 KB coalesced per load) with rolling register prefetch;
// A-block (32 KB) staged once in LDS.
__global__ __launch_bounds__(512, 2)
void gemm_softmax_kernel(const ushort* __restrict__ Fp,
                         const ushort* __restrict__ Ps,
                         const float* __restrict__ f2,
                         const float* __restrict__ p2,
                         float* __restrict__ out) {
    __shared__ ushort Ab[16384];         // 32 KB packed A image for this block
    __shared__ float partial[8][BM];
    __shared__ float inv_total[BM];

    const int tid = threadIdx.x;
    const int wid = tid >> 6;
    const int ln  = tid & 63;
    const int lr  = ln & 15;
    const int lg  = ln >> 4;
    const int row0 = blockIdx.x * BM;

    // stage packed A image (linear copy, 4 x 8KB rounds), one barrier
    {
        const ushort* src = Fp + (size_t)blockIdx.x * 16384;
        #pragma unroll
        for (int r = 0; r < 4; ++r)
            gload16(src + r * 4096 + tid * 8, (char*)Ab + r * 8192 + wid * 1024);
    }

    f4v acc[2][16];
    #pragma unroll
    for (int rt = 0; rt < 2; ++rt)
        #pragma unroll
        for (int i = 0; i < 16; ++i)
            acc[rt][i] = (f4v){0.f, 0.f, 0.f, 0.f};

    // wave's B base: tile (wid*16 + i), chunk c at ushort (tile*16 + c)*512 + ln*8
    const ushort* wb = Ps + (size_t)wid * 16 * 16 * 512 + ln * 8;

    s8v bfrag[16];
    #pragma unroll
    for (int i = 0; i < 16; ++i)
        bfrag[i] = *reinterpret_cast<const s8v*>(wb + (size_t)(i * 16) * 512);

    __syncthreads();   // A image ready (waits vmcnt(0) too)

    #pragma unroll
    for (int c = 0; c < 16; ++c) {
        s8v a0 = *reinterpret_cast<const s8v*>(Ab + c * 1024 + lr * 32 + lg * 8);
        s8v a1 = *reinterpret_cast<const s8v*>(Ab + c * 1024 + (16 + lr) * 32 + lg * 8);
        #pragma unroll
        for (int i = 0; i < 16; ++i) {
            s8v b = bfrag[i];
            if (c < 15)
                bfrag[i] = *reinterpret_cast<const s8v*>(wb + (size_t)(i * 16 + c + 1) * 512);
            acc[0][i] = __builtin_amdgcn_mfma_f32_16x16x32_bf16(a0, b, acc[0][i], 0, 0, 0);
            acc[1][i] = __builtin_amdgcn_mfma_f32_16x16x32_bf16(a1, b, acc[1][i], 0, 0, 0);
        }
    }

    // ---- epilogue: sq = f2 + p2 - 2*fp ; sim = 1/(1+sqrt(sq)) ; softmax ----
    float pf2[2][4];
    #pragma unroll
    for (int rt = 0; rt < 2; ++rt)
        #pragma unroll
        for (int r = 0; r < 4; ++r)
            pf2[rt][r] = f2[row0 + rt * 16 + 4 * lg + r];

    float pp2[16];
    #pragma unroll
    for (int i = 0; i < 16; ++i)
        pp2[i] = p2[wid * 256 + i * 16 + lr];

    float rsum[2][4] = {{0.f, 0.f, 0.f, 0.f}, {0.f, 0.f, 0.f, 0.f}};
    #pragma unroll
    for (int rt = 0; rt < 2; ++rt)
        #pragma unroll
        for (int i = 0; i < 16; ++i)
            #pragma unroll
            for (int r = 0; r < 4; ++r) {
                float sq = pf2[rt][r] + pp2[i] - 2.0f * acc[rt][i][r];
                sq = fmaxf(sq, 0.0f);
                float dist = sqrtf(sq);
                float e = __expf(1.0f / (1.0f + dist));
                acc[rt][i][r] = e;
                rsum[rt][r] += e;
            }

    #pragma unroll
    for (int rt = 0; rt < 2; ++rt)
        #pragma unroll
        for (int r = 0; r < 4; ++r) {
            float v = rsum[rt][r];
            #pragma unroll
            for (int m = 1; m < 16; m <<= 1) v += __shfl_xor(v, m, 64);
            rsum[rt][r] = v;
        }

    if (lr == 0) {
        #pragma unroll
        for (int rt = 0; rt < 2; ++rt)
            #pragma unroll
            for (int r = 0; r < 4; ++r)
                partial[wid][rt * 16 + 4 * lg + r] = rsum[rt][r];
    }
    __syncthreads();

    if (tid < BM) {
        float s = 0.f;
        #pragma unroll
        for (int w = 0; w < 8; ++w) s += partial[w][tid];
        inv_total[tid] = 1.0f / s;
    }
    __syncthreads();

    float pinv[2][4];
    #pragma unroll
    for (int rt = 0; rt < 2; ++rt)
        #pragma unroll
        for (int r = 0; r < 4; ++r)
            pinv[rt][r] = inv_total[rt * 16 + 4 * lg + r];

    #pragma unroll
    for (int rt = 0; rt < 2; ++rt)
        #pragma unroll
        for (int i = 0; i < 16; ++i)
            #pragma unroll
            for (int r = 0; r < 4; ++r) {
                const int row = row0 + rt * 16 + 4 * lg + r;
                const int col = wid * 256 + i * 16 + lr;
                out[(size_t)row * K_CL + col] = acc[rt][i][r] * pinv[rt][r];
            }
}

extern "C" void kernel_launch(void* const* d_in, const int* in_sizes, int n_in,
                              void* d_out, int out_size, void* d_ws, size_t ws_size,
                              hipStream_t stream) {
    const float* features   = (const float*)d_in[0];
    const float* prototypes = (const float*)d_in[1];
    float* out = (float*)d_out;

    const int n = in_sizes[0] / D_DIM;   // 32768
    const int k = in_sizes[1] / D_DIM;   // 2048

    char* ws = (char*)d_ws;
    ushort* Fp = (ushort*)ws;                                    // n*D*2 bytes (packed A)
    ushort* Ps = (ushort*)(ws + (size_t)n * D_DIM * 2);          // k*D*2 bytes (packed B)
    float*  f2 = (float*)(ws + (size_t)(n + k) * D_DIM * 2);     // n floats
    float*  p2 = f2 + n;                                         // k floats

    prep_f_kernel<<<dim3((n + 3) / 4), dim3(256), 0, stream>>>(features, Fp, f2, n);
    prep_p_kernel<<<dim3(k / 16), dim3(256), 0, stream>>>(prototypes, Ps, p2);

    gemm_softmax_kernel<<<dim3(n / BM), dim3(512), 0, stream>>>(Fp, Ps, f2, p2, out);
}

// Round 5
// 208.439 us; speedup vs baseline: 1.5711x; 1.5711x over previous
//
#include <hip/hip_runtime.h>
#include <hip/hip_bf16.h>

#define D_DIM 512
#define K_CL  2048

#define AS1 __attribute__((address_space(1)))
#define AS3 __attribute__((address_space(3)))

typedef short s8v __attribute__((ext_vector_type(8)));
typedef float f4v __attribute__((ext_vector_type(4)));

__device__ __forceinline__ void gload16(const void* g, void* l) {
    // async global->LDS, 16B/lane; LDS dest = wave-uniform base + lane*16
    __builtin_amdgcn_global_load_lds((const AS1 void*)g, (AS3 void*)l, 16, 0, 0);
}

// ---- prep: fp32 -> bf16 packed-tile image + row sum-of-squares -------------
// Packed image: per 128-row panel pb, per 32-k chunk c (16 chunks): a 4096-
// ushort block at (pb*16 + c)*4096; within: row r (0..127) at r*32, k-octet j
// stored at swizzled slot (j ^ ((r>>1)&3))*8.  One wave per source row.
__global__ void prep_kernel(const float* __restrict__ src,
                            ushort* __restrict__ dst,
                            float* __restrict__ norms,
                            int nrows) {
    int row  = (int)((blockIdx.x * blockDim.x + threadIdx.x) >> 6);
    int lane = threadIdx.x & 63;
    if (row >= nrows) return;

    const float* s = src + (size_t)row * D_DIM + lane * 8;
    float4 v0 = *reinterpret_cast<const float4*>(s);
    float4 v1 = *reinterpret_cast<const float4*>(s + 4);

    float ss = v0.x * v0.x + v0.y * v0.y + v0.z * v0.z + v0.w * v0.w
             + v1.x * v1.x + v1.y * v1.y + v1.z * v1.z + v1.w * v1.w;

    alignas(16) __hip_bfloat16 h[8];
    h[0] = __float2bfloat16(v0.x); h[1] = __float2bfloat16(v0.y);
    h[2] = __float2bfloat16(v0.z); h[3] = __float2bfloat16(v0.w);
    h[4] = __float2bfloat16(v1.x); h[5] = __float2bfloat16(v1.y);
    h[6] = __float2bfloat16(v1.z); h[7] = __float2bfloat16(v1.w);

    // lane covers k = lane*8..+7 -> chunk c = lane>>2, octet j = lane&3
    const int r   = row & 127;
    const size_t di = ((size_t)((row >> 7) * 16 + (lane >> 2)) * 128 + r) * 32
                    + (((lane & 3) ^ ((r >> 1) & 3)) << 3);
    *reinterpret_cast<uint4*>(dst + di) = *reinterpret_cast<const uint4*>(h);

    #pragma unroll
    for (int off = 32; off > 0; off >>= 1) ss += __shfl_down(ss, off, 64);
    if (lane == 0) norms[row] = ss;
}

// ---- pass 1: 128x128-tile bf16 GEMM (m97-style) + e=exp(sim) + partial sums
// 4 waves (2x2 of 64x64), BK=64 (2 x 32-k chunks per step), single-buffered
// LDS, 2 barriers/step; multi-block-per-CU overlap hides the stage drain.
// Writes e as bf16 into out-row slot bytes [8192*row, +4096) and per-block
// row partial sums to partial[row*16 + cb].
__global__ __launch_bounds__(256, 3)
void gemm_pass1(const ushort* __restrict__ Fp,
                const ushort* __restrict__ Pp,
                const float* __restrict__ f2,
                const float* __restrict__ p2,
                ushort* __restrict__ eb,
                float* __restrict__ partial) {
    __shared__ ushort At[8192];     // 16 KB: [kk][128 r][32 k swizzled]
    __shared__ ushort Bt[8192];     // 16 KB
    __shared__ float rsums[128][2];

    const int tid = threadIdx.x;
    const int wid = tid >> 6;
    const int ln  = tid & 63;
    const int lr  = ln & 15;
    const int lg  = ln >> 4;
    const int wr  = wid >> 1;       // wave row 0..1
    const int wc  = wid & 1;        // wave col 0..1

    // XCD-chunked bijective swizzle (nwg=4096, 4096%8==0): each XCD gets 512
    // consecutive wg -> 32 contiguous row-panels; cb fastest within XCD.
    const int orig = blockIdx.x;
    const int wg   = (orig & 7) * 512 + (orig >> 3);
    const int rb   = wg >> 4;
    const int cb   = wg & 15;
    const int row0 = rb * 128;
    const int col0 = cb * 128;

    const ushort* Asrc = Fp + (size_t)rb * 16 * 4096;
    const ushort* Bsrc = Pp + (size_t)cb * 16 * 4096;

    auto stage = [&](int c) {   // stage chunks 2c,2c+1: 16 KB A + 16 KB B
        #pragma unroll
        for (int h = 0; h < 4; ++h) {
            gload16(Asrc + (size_t)(2 * c) * 4096 + h * 2048 + tid * 8,
                    (char*)At + h * 4096 + wid * 1024);
            gload16(Bsrc + (size_t)(2 * c) * 4096 + h * 2048 + tid * 8,
                    (char*)Bt + h * 4096 + wid * 1024);
        }
    };

    f4v acc[4][4];
    #pragma unroll
    for (int m = 0; m < 4; ++m)
        #pragma unroll
        for (int n = 0; n < 4; ++n)
            acc[m][n] = (f4v){0.f, 0.f, 0.f, 0.f};

    stage(0);
    const int swz = (lg ^ ((lr >> 1) & 3)) << 4;   // swizzled 16B slot offset

    for (int c = 0; c < 8; ++c) {
        __syncthreads();                 // stage c landed (drains vmcnt)
        #pragma unroll
        for (int kk = 0; kk < 2; ++kk) {
            s8v af[4], bf[4];
            #pragma unroll
            for (int m = 0; m < 4; ++m)
                af[m] = *reinterpret_cast<const s8v*>(
                    (const char*)At + kk * 8192 + (wr * 64 + m * 16 + lr) * 64 + swz);
            #pragma unroll
            for (int n = 0; n < 4; ++n)
                bf[n] = *reinterpret_cast<const s8v*>(
                    (const char*)Bt + kk * 8192 + (wc * 64 + n * 16 + lr) * 64 + swz);
            #pragma unroll
            for (int m = 0; m < 4; ++m)
                #pragma unroll
                for (int n = 0; n < 4; ++n)
                    acc[m][n] = __builtin_amdgcn_mfma_f32_16x16x32_bf16(
                        af[m], bf[n], acc[m][n], 0, 0, 0);
        }
        __syncthreads();                 // all LDS reads done
        if (c < 7) stage(c + 1);
    }

    // ---- epilogue: e = exp(1/(1+sqrt(f2+p2-2fp))), bf16-store + row sums ---
    float pf2v[4][4];
    #pragma unroll
    for (int m = 0; m < 4; ++m)
        #pragma unroll
        for (int r = 0; r < 4; ++r)
            pf2v[m][r] = f2[row0 + wr * 64 + m * 16 + 4 * lg + r];

    float pp2v[4];
    #pragma unroll
    for (int n = 0; n < 4; ++n)
        pp2v[n] = p2[col0 + wc * 64 + n * 16 + lr];

    float rs[4][4];
    #pragma unroll
    for (int m = 0; m < 4; ++m)
        #pragma unroll
        for (int r = 0; r < 4; ++r)
            rs[m][r] = 0.f;

    #pragma unroll
    for (int m = 0; m < 4; ++m)
        #pragma unroll
        for (int n = 0; n < 4; ++n)
            #pragma unroll
            for (int r = 0; r < 4; ++r) {
                float sq = pf2v[m][r] + pp2v[n] - 2.0f * acc[m][n][r];
                sq = fmaxf(sq, 0.0f);
                float e = __expf(1.0f / (1.0f + sqrtf(sq)));
                rs[m][r] += e;
                const int grow = row0 + wr * 64 + m * 16 + 4 * lg + r;
                const int gcol = col0 + wc * 64 + n * 16 + lr;
                eb[(size_t)grow * 4096 + gcol] =
                    __builtin_bit_cast(ushort, __float2bfloat16(e));
            }

    #pragma unroll
    for (int m = 0; m < 4; ++m)
        #pragma unroll
        for (int r = 0; r < 4; ++r) {
            float v = rs[m][r];
            #pragma unroll
            for (int msk = 1; msk < 16; msk <<= 1) v += __shfl_xor(v, msk, 64);
            rs[m][r] = v;
        }

    if (lr == 0) {
        #pragma unroll
        for (int m = 0; m < 4; ++m)
            #pragma unroll
            for (int r = 0; r < 4; ++r)
                rsums[wr * 64 + m * 16 + 4 * lg + r][wc] = rs[m][r];
    }
    __syncthreads();

    if (tid < 128)
        partial[(size_t)(row0 + tid) * 16 + cb] = rsums[tid][0] + rsums[tid][1];
}

// ---- pass 2: per-row normalize. e (bf16) lives in the row's own out slot:
// bytes [8192r, 8192r+4096). Read ALL of the row first, then write fp32 —
// only self-row overlap by construction, so within-wave ordering suffices.
__global__ __launch_bounds__(256)
void scale_kernel(const float* __restrict__ partial, float* __restrict__ out) {
    const ushort* eb = (const ushort*)out;
    const int wid = threadIdx.x >> 6;
    const int ln  = threadIdx.x & 63;
    const int row = blockIdx.x * 4 + wid;

    float p = partial[(size_t)row * 16 + (ln & 15)];
    #pragma unroll
    for (int msk = 1; msk < 16; msk <<= 1) p += __shfl_xor(p, msk, 64);
    const float inv = 1.0f / p;

    s8v v[4];
    #pragma unroll
    for (int it = 0; it < 4; ++it)
        v[it] = *reinterpret_cast<const s8v*>(eb + (size_t)row * 4096 + it * 512 + ln * 8);

    #pragma unroll
    for (int it = 0; it < 4; ++it) {
        float4 w0, w1;
        w0.x = __uint_as_float((unsigned)(ushort)v[it][0] << 16) * inv;
        w0.y = __uint_as_float((unsigned)(ushort)v[it][1] << 16) * inv;
        w0.z = __uint_as_float((unsigned)(ushort)v[it][2] << 16) * inv;
        w0.w = __uint_as_float((unsigned)(ushort)v[it][3] << 16) * inv;
        w1.x = __uint_as_float((unsigned)(ushort)v[it][4] << 16) * inv;
        w1.y = __uint_as_float((unsigned)(ushort)v[it][5] << 16) * inv;
        w1.z = __uint_as_float((unsigned)(ushort)v[it][6] << 16) * inv;
        w1.w = __uint_as_float((unsigned)(ushort)v[it][7] << 16) * inv;
        float* o = out + (size_t)row * 2048 + it * 512 + ln * 8;
        *reinterpret_cast<float4*>(o)     = w0;
        *reinterpret_cast<float4*>(o + 4) = w1;
    }
}

extern "C" void kernel_launch(void* const* d_in, const int* in_sizes, int n_in,
                              void* d_out, int out_size, void* d_ws, size_t ws_size,
                              hipStream_t stream) {
    const float* features   = (const float*)d_in[0];
    const float* prototypes = (const float*)d_in[1];
    float* out = (float*)d_out;

    const int n = in_sizes[0] / D_DIM;   // 32768
    const int k = in_sizes[1] / D_DIM;   // 2048

    char* ws = (char*)d_ws;
    ushort* Fp = (ushort*)ws;                                  // 32 MB packed F
    ushort* Pp = (ushort*)(ws + (size_t)n * D_DIM * 2);        // 2 MB packed P
    float*  f2 = (float*)(ws + (size_t)(n + k) * D_DIM * 2);   // n floats
    float*  p2 = f2 + n;                                       // k floats
    float*  partial = p2 + k;                                  // n*16 floats (2 MB)

    prep_kernel<<<dim3((n + 3) / 4), dim3(256), 0, stream>>>(features, Fp, f2, n);
    prep_kernel<<<dim3((k + 3) / 4), dim3(256), 0, stream>>>(prototypes, Pp, p2, k);

    const int nwg = (n / 128) * (k / 128);   // 4096
    gemm_pass1<<<dim3(nwg), dim3(256), 0, stream>>>(Fp, Pp, f2, p2,
                                                    (ushort*)d_out, partial);

    scale_kernel<<<dim3(n / 4), dim3(256), 0, stream>>>(partial, out);
}